// Round 17
// baseline (246.088 us; speedup 1.0000x reference)
//
#include <hip/hip_runtime.h>
#include <hip/hip_bf16.h>

#define N_NODES    100000
#define N_EDGES    1200000
#define NUM_GRAPHS 128
#define IN_DIM     5
#define HIDDEN     64
#define M_TILES    (N_NODES / 16)   // 6250 (exact)
#define NI4        (N_EDGES / 4)    // 300000 int4 groups

#define CB    782                   // coarse buckets: ceil(N/128)
#define CBLK  256                   // partition blocks
#define EPB   ((NI4 + CBLK - 1) / CBLK)   // 1172 int4-groups per block

typedef __attribute__((ext_vector_type(8))) short short8;   // 8 bf16 (4 VGPRs)
typedef __attribute__((ext_vector_type(4))) float f32x4;

__device__ __forceinline__ int rfl(int v) { return __builtin_amdgcn_readfirstlane(v); }

// fp32 -> bf16 bits (RNE)
__device__ __forceinline__ unsigned short f2bs(float f) {
    union { float f; unsigned u; } v; v.f = f;
    return (unsigned short)((v.u + 0x7FFFu + ((v.u >> 16) & 1u)) >> 16);
}
// bf16 bits -> fp32
__device__ __forceinline__ float bs2f(unsigned short s) {
    union { unsigned u; float f; } v; v.u = ((unsigned)s) << 16;
    return v.f;
}
__device__ __forceinline__ float blo(unsigned p) { return bs2f((unsigned short)(p & 0xffff)); }
__device__ __forceinline__ float bhi(unsigned p) { return bs2f((unsigned short)(p >> 16)); }
__device__ __forceinline__ unsigned pack2(float a, float b) {
    return ((unsigned)f2bs(b) << 16) | (unsigned)f2bs(a);
}

// fp32 (>=0) -> fp8 e4m3 bits, RNE, denorm-exact (magic-multiply trick)
__device__ __forceinline__ unsigned char f2f8(float f) {
    union { float f; unsigned u; } v; v.f = f * 0x1p-120f;
    unsigned u = v.u + 0x7FFFFu + ((v.u >> 20) & 1u);
    return (unsigned char)(u >> 20);
}
// fp8 e4m3 bits -> fp32 (exact inverse)
__device__ __forceinline__ float f82f(unsigned b) {
    union { unsigned u; float f; } v; v.u = (b & 0x7Fu) << 20;
    return v.f * 0x1p120f;
}

// ==================== CSR build: two-level counting sort ====================
// part entries are PACKED 4B: src (bits 0..16) | (dst & 127) << 17.

// ---- Pass A: coarse histogram (dst>>7) + packx fold ------------------------
__global__ void coarse_count(const int* __restrict__ dst, int* __restrict__ gcnt,
                             const float* __restrict__ x, uint4* __restrict__ xb) {
    __shared__ int h[CB];
    int t = threadIdx.x, b = blockIdx.x;
    for (int i = t; i < CB; i += 256) h[i] = 0;
    __syncthreads();
    int i0 = b * EPB, i1 = min(i0 + EPB, NI4);
    for (int i = i0 + t; i < i1; i += 256) {
        int4 d = ((const int4*)dst)[i];
        atomicAdd(&h[d.x >> 7], 1);
        atomicAdd(&h[d.y >> 7], 1);
        atomicAdd(&h[d.z >> 7], 1);
        atomicAdd(&h[d.w >> 7], 1);
    }
    __syncthreads();
    for (int i = t; i < CB; i += 256) gcnt[b * CB + i] = h[i];

    // fold: pack x rows into 16B (5 bf16 + pad) for the layer-1 edge gather
    for (int n = b * 256 + t; n < N_NODES; n += CBLK * 256) {
        const float* xr = x + (size_t)n * IN_DIM;
        uint4 o;
        o.x = pack2(xr[0], xr[1]);
        o.y = pack2(xr[2], xr[3]);
        o.z = pack2(xr[4], 0.0f);
        o.w = 0u;
        xb[n] = o;
    }
}

// ---- Pass B1: per-bucket exclusive scan over the 256 blocks ---------------
__global__ void block_scan(int* __restrict__ gcnt, int* __restrict__ btot) {
    __shared__ int s[CBLK];
    int k = blockIdx.x, t = threadIdx.x;
    int v = gcnt[t * CB + k];
    s[t] = v;
    __syncthreads();
    for (int off = 1; off < CBLK; off <<= 1) {
        int x = (t >= off) ? s[t - off] : 0;
        __syncthreads();
        s[t] += x;
        __syncthreads();
    }
    gcnt[t * CB + k] = s[t] - v;
    if (t == CBLK - 1) btot[k] = s[t];
}

// ---- Pass B2: scan bucket totals -> bstart; also zero add_pool -------------
__global__ void bucket_scan(const int* __restrict__ btot, int* __restrict__ bstart,
                            float* __restrict__ add_pool) {
    __shared__ int s[1024];
    int t = threadIdx.x;
    int v = (t < CB) ? btot[t] : 0;
    s[t] = v;
    __syncthreads();
    for (int off = 1; off < 1024; off <<= 1) {
        int x = (t >= off) ? s[t - off] : 0;
        __syncthreads();
        s[t] += x;
        __syncthreads();
    }
    if (t < CB) bstart[t] = s[t] - v;
    if (t == 0) bstart[CB] = N_EDGES;
    for (int i = t; i < NUM_GRAPHS * HIDDEN; i += 1024) add_pool[i] = 0.0f;
}

// ---- Pass C: partition edges into coarse-bucket order (packed 4B) ----------
__global__ void partition_k(const int* __restrict__ src, const int* __restrict__ dst,
                            const int* __restrict__ gcnt, const int* __restrict__ bstart,
                            int* __restrict__ part) {
    __shared__ int base[CB];
    __shared__ int h[CB];
    int t = threadIdx.x, b = blockIdx.x;
    for (int i = t; i < CB; i += 256) {
        base[i] = bstart[i] + gcnt[b * CB + i];
        h[i] = 0;
    }
    __syncthreads();
    int i0 = b * EPB, i1 = min(i0 + EPB, NI4);
    for (int i = i0 + t; i < i1; i += 256) {
        int4 s4 = ((const int4*)src)[i];
        int4 d4 = ((const int4*)dst)[i];
        int k, r;
        k = d4.x >> 7; r = atomicAdd(&h[k], 1); part[base[k] + r] = s4.x | ((d4.x & 127) << 17);
        k = d4.y >> 7; r = atomicAdd(&h[k], 1); part[base[k] + r] = s4.y | ((d4.y & 127) << 17);
        k = d4.z >> 7; r = atomicAdd(&h[k], 1); part[base[k] + r] = s4.z | ((d4.z & 127) << 17);
        k = d4.w >> 7; r = atomicAdd(&h[k], 1); part[base[k] + r] = s4.w | ((d4.w & 127) << 17);
    }
}

// ---- Pass D: fine sort within each 128-node bucket -> ptr + esrc -----------
__global__ void fine_sort(const int* __restrict__ part, const int* __restrict__ bstart,
                          int* __restrict__ ptr, int* __restrict__ esrc) {
    __shared__ int fh[128];
    __shared__ int fr[128];
    int k = blockIdx.x, t = threadIdx.x;
    int e0 = bstart[k], e1 = bstart[k + 1];
    if (t < 128) { fh[t] = 0; fr[t] = 0; }
    __syncthreads();
    for (int e = e0 + t; e < e1; e += 256)
        atomicAdd(&fh[(part[e] >> 17) & 127], 1);
    __syncthreads();
    if (t == 0) {
        int run = 0;
        for (int i = 0; i < 128; ++i) { int c = fh[i]; fh[i] = run; run += c; }
    }
    __syncthreads();
    int n0 = k << 7;
    if (t < 128 && n0 + t < N_NODES) ptr[n0 + t] = e0 + fh[t];
    for (int e = e0 + t; e < e1; e += 256) {
        int p = part[e];
        int d = (p >> 17) & 127;
        int r = atomicAdd(&fr[d], 1);
        esrc[e0 + fh[d] + r] = p & 0x1FFFF;
    }
}

// ==================== GNN compute ===========================================

// ---- Layer 1: gather agg1 (ONE uint4 load per edge) + transform ------------
__global__ void gather_mlp1(const uint4* __restrict__ xb,
                            const float* __restrict__ x,
                            const int* __restrict__ ptr,
                            const int* __restrict__ esrc,
                            const float* __restrict__ w_rel1,
                            const float* __restrict__ b_rel1,
                            const float* __restrict__ w_root1,
                            unsigned short* __restrict__ h1,
                            unsigned char* __restrict__ h1f8) {
    int lane = threadIdx.x & 63;
    int w    = (blockIdx.x * blockDim.x + threadIdx.x) >> 6;
    int nw   = (gridDim.x * blockDim.x) >> 6;

    float wr[IN_DIM], wo[IN_DIM];
#pragma unroll
    for (int k = 0; k < IN_DIM; ++k) {
        wr[k] = w_rel1[k * HIDDEN + lane];
        wo[k] = w_root1[k * HIDDEN + lane];
    }
    float bias = b_rel1[lane];

    for (int n = w; n < N_NODES; n += nw) {
        int start = rfl(ptr[n]);
        int end   = rfl((n + 1 < N_NODES) ? ptr[n + 1] : N_EDGES);
        float a[IN_DIM] = {0.f, 0.f, 0.f, 0.f, 0.f};
        for (int e = start + lane; e < end; e += 64) {
            uint4 p = xb[esrc[e]];
            a[0] += blo(p.x); a[1] += bhi(p.x);
            a[2] += blo(p.y); a[3] += bhi(p.y);
            a[4] += blo(p.z);
        }
#pragma unroll
        for (int k = 0; k < IN_DIM; ++k)
#pragma unroll
            for (int off = 1; off < 64; off <<= 1)
                a[k] += __shfl_xor(a[k], off, 64);
        float acc = bias;
#pragma unroll
        for (int k = 0; k < IN_DIM; ++k)
            acc += a[k] * wr[k] + x[(size_t)n * IN_DIM + k] * wo[k];
        float hv = fmaxf(acc, 0.0f);
        h1[(size_t)n * HIDDEN + lane]   = f2bs(hv);
        h1f8[(size_t)n * HIDDEN + lane] = f2f8(hv);
    }
}

// ---- FUSED Layer 2: fp8 row-gather -> LDS tile -> MFMA -> pooled epilogue --
// Block = 4 waves = one 16-node tile per iteration. Gather phase: wave wv
// gathers agg rows for nodes wv*4..wv*4+3 (quarter-wave per node, 4 edges in
// flight), stages bf16 rows in LDS (stride 72 shorts: b128-aligned reads).
// MFMA phase: A-frags from LDS, root-term from global h1, pool epilogue.
#define TSTRIDE 72
__global__ void gather2_mlp2_pool(const unsigned* __restrict__ h1f8,  // row = 16 dwords
                                  const int* __restrict__ ptr,
                                  const int* __restrict__ esrc,
                                  const unsigned short* __restrict__ h1,
                                  const float* __restrict__ w_rel2,
                                  const float* __restrict__ b_rel2,
                                  const float* __restrict__ w_root2,
                                  const int* __restrict__ batch,
                                  float* __restrict__ add_pool) {
    __shared__ unsigned short tile[16 * TSTRIDE];   // agg rows, bf16
    int lane = threadIdx.x & 63;
    int wv   = threadIdx.x >> 6;        // 0..3
    int ql   = lane & 15;               // dword index within a row (gather)
    int q    = lane >> 4;               // edge slot (gather)
    int row  = lane & 15;               // MFMA row
    int quad = lane >> 4;               // MFMA quad
    int ncol = wv * 16 + row;           // output column

    short8 bwr[2], bwo[2];
#pragma unroll
    for (int s = 0; s < 2; ++s)
#pragma unroll
        for (int j = 0; j < 8; ++j) {
            int k = 32 * s + quad * 8 + j;
            bwr[s][j] = (short)f2bs(w_rel2[k * HIDDEN + ncol]);
            bwo[s][j] = (short)f2bs(w_root2[k * HIDDEN + ncol]);
        }
    float bias = b_rel2[ncol];

    for (int t = blockIdx.x; t < M_TILES; t += gridDim.x) {
        int m0 = t * 16;

        // ---- gather phase: 4 nodes per wave ----
#pragma unroll
        for (int ii = 0; ii < 4; ++ii) {
            int n = m0 + wv * 4 + ii;
            int start = rfl(ptr[n]);
            int end   = rfl((n + 1 < N_NODES) ? ptr[n + 1] : N_EDGES);
            float4 a0 = {0.f,0.f,0.f,0.f}, a1 = a0, a2 = a0, a3 = a0;
            int e = start + q;
            for (; e + 12 < end; e += 16) {
                int s0 = esrc[e], s1 = esrc[e + 4], s2 = esrc[e + 8], s3 = esrc[e + 12];
                unsigned p0 = h1f8[(size_t)s0 * 16 + ql];
                unsigned p1 = h1f8[(size_t)s1 * 16 + ql];
                unsigned p2 = h1f8[(size_t)s2 * 16 + ql];
                unsigned p3 = h1f8[(size_t)s3 * 16 + ql];
                a0.x += f82f(p0); a0.y += f82f(p0 >> 8); a0.z += f82f(p0 >> 16); a0.w += f82f(p0 >> 24);
                a1.x += f82f(p1); a1.y += f82f(p1 >> 8); a1.z += f82f(p1 >> 16); a1.w += f82f(p1 >> 24);
                a2.x += f82f(p2); a2.y += f82f(p2 >> 8); a2.z += f82f(p2 >> 16); a2.w += f82f(p2 >> 24);
                a3.x += f82f(p3); a3.y += f82f(p3 >> 8); a3.z += f82f(p3 >> 16); a3.w += f82f(p3 >> 24);
            }
            for (; e < end; e += 4) {
                unsigned p = h1f8[(size_t)esrc[e] * 16 + ql];
                a0.x += f82f(p); a0.y += f82f(p >> 8); a0.z += f82f(p >> 16); a0.w += f82f(p >> 24);
            }
            float4 a;
            a.x = (a0.x + a1.x) + (a2.x + a3.x);
            a.y = (a0.y + a1.y) + (a2.y + a3.y);
            a.z = (a0.z + a1.z) + (a2.z + a3.z);
            a.w = (a0.w + a1.w) + (a2.w + a3.w);
            a.x += __shfl_xor(a.x, 16, 64); a.x += __shfl_xor(a.x, 32, 64);
            a.y += __shfl_xor(a.y, 16, 64); a.y += __shfl_xor(a.y, 32, 64);
            a.z += __shfl_xor(a.z, 16, 64); a.z += __shfl_xor(a.z, 32, 64);
            a.w += __shfl_xor(a.w, 16, 64); a.w += __shfl_xor(a.w, 32, 64);
            if (q == 0) {
                uint2 o;
                o.x = pack2(a.x, a.y);
                o.y = pack2(a.z, a.w);
                *(uint2*)&tile[(wv * 4 + ii) * TSTRIDE + ql * 4] = o;
            }
        }
        __syncthreads();

        // ---- MFMA + pool phase ----
        short8 aa0 = *(const short8*)&tile[row * TSTRIDE + quad * 8];
        short8 aa1 = *(const short8*)&tile[row * TSTRIDE + 32 + quad * 8];
        size_t rbase = (size_t)(m0 + row) * HIDDEN;
        short8 ah0 = *(const short8*)(h1 + rbase + quad * 8);
        short8 ah1 = *(const short8*)(h1 + rbase + 32 + quad * 8);

        f32x4 acc = {bias, bias, bias, bias};
        acc = __builtin_amdgcn_mfma_f32_16x16x32_bf16(aa0, bwr[0], acc, 0, 0, 0);
        acc = __builtin_amdgcn_mfma_f32_16x16x32_bf16(aa1, bwr[1], acc, 0, 0, 0);
        acc = __builtin_amdgcn_mfma_f32_16x16x32_bf16(ah0, bwo[0], acc, 0, 0, 0);
        acc = __builtin_amdgcn_mfma_f32_16x16x32_bf16(ah1, bwo[1], acc, 0, 0, 0);

        float hv0 = fmaxf(acc[0], 0.0f), hv1 = fmaxf(acc[1], 0.0f);
        float hv2 = fmaxf(acc[2], 0.0f), hv3 = fmaxf(acc[3], 0.0f);

        int gLo = batch[m0], gHi = batch[m0 + 15];
        if (gLo == gHi) {
            float s = (hv0 + hv1) + (hv2 + hv3);
            s += __shfl_xor(s, 16, 64);
            s += __shfl_xor(s, 32, 64);
            if (quad == 0)
                atomicAdd(&add_pool[gLo * HIDDEN + ncol], s);
        } else {
            int m = m0 + quad * 4;
            atomicAdd(&add_pool[batch[m]     * HIDDEN + ncol], hv0);
            atomicAdd(&add_pool[batch[m + 1] * HIDDEN + ncol], hv1);
            atomicAdd(&add_pool[batch[m + 2] * HIDDEN + ncol], hv2);
            atomicAdd(&add_pool[batch[m + 3] * HIDDEN + ncol], hv3);
        }
        __syncthreads();   // tile reuse
    }
}

// ---- MLP head: one block (64 threads) per graph ----------------------------
__device__ __forceinline__ int lower_bound_i(const int* a, int n, int v) {
    int lo = 0, hi = n;
    while (lo < hi) { int mid = (lo + hi) >> 1; if (a[mid] < v) lo = mid + 1; else hi = mid; }
    return lo;
}

__global__ void head_mlp(const float* __restrict__ add_pool,
                         const int* __restrict__ batch,
                         const float* __restrict__ w_h1,
                         const float* __restrict__ b_h1,
                         const float* __restrict__ w_h2,
                         const float* __restrict__ b_h2,
                         float* __restrict__ out) {
    int g = blockIdx.x, t = threadIdx.x;

    __shared__ int s_cnt;
    if (t == 0) {
        int start = lower_bound_i(batch, N_NODES, g);
        int end   = lower_bound_i(batch, N_NODES, g + 1);
        s_cnt = end - start;
    }
    __syncthreads();
    float cnt = fmaxf((float)s_cnt, 1.0f);

    __shared__ float sg[2 * HIDDEN];
    float add = add_pool[(size_t)g * HIDDEN + t];
    sg[t]          = add / cnt;   // mean_pool
    sg[HIDDEN + t] = add;         // add_pool
    __syncthreads();

    float hid = b_h1[t];
#pragma unroll 16
    for (int i = 0; i < 2 * HIDDEN; ++i)
        hid += sg[i] * w_h1[i * HIDDEN + t];
    hid = fmaxf(hid, 0.0f);

    float res = hid * w_h2[t];
    for (int off = 32; off > 0; off >>= 1)
        res += __shfl_down(res, off, 64);
    if (t == 0) out[g] = res + b_h2[0];
}

extern "C" void kernel_launch(void* const* d_in, const int* in_sizes, int n_in,
                              void* d_out, int out_size, void* d_ws, size_t ws_size,
                              hipStream_t stream) {
    const float* x       = (const float*)d_in[0];
    const int*   ei      = (const int*)d_in[1];
    const int*   src     = ei;
    const int*   dst     = ei + N_EDGES;
    const int*   batch   = (const int*)d_in[2];
    const float* w_rel1  = (const float*)d_in[3];
    const float* b_rel1  = (const float*)d_in[4];
    const float* w_root1 = (const float*)d_in[5];
    const float* w_rel2  = (const float*)d_in[6];
    const float* b_rel2  = (const float*)d_in[7];
    const float* w_root2 = (const float*)d_in[8];
    const float* w_h1    = (const float*)d_in[9];
    const float* b_h1    = (const float*)d_in[10];
    const float* w_h2    = (const float*)d_in[11];
    const float* b_h2    = (const float*)d_in[12];
    float* out = (float*)d_out;

    int* base = (int*)d_ws;
    int*   gcnt     = base;                                   // CBLK*CB
    int*   btot     = gcnt + ((CBLK * CB + 3) & ~3);          // CB
    int*   bstart   = btot + ((CB + 3) & ~3);                 // CB+1
    float* add_pool = (float*)(bstart + ((CB + 1 + 3) & ~3)); // 128*64 f32
    int*   ptr      = (int*)(add_pool + NUM_GRAPHS * HIDDEN); // N
    int*   part     = ptr + ((N_NODES + 3) & ~3);             // E packed ints
    int*   esrc     = part + N_EDGES;                         // E
    unsigned short* h1   = (unsigned short*)(esrc + N_EDGES); // N*64 bf16
    unsigned char*  h1f8 = (unsigned char*)(h1 + (size_t)N_NODES * HIDDEN); // N*64 fp8
    uint4*          xb   = (uint4*)(h1f8 + (size_t)N_NODES * HIDDEN);       // N*16B

    // ---- CSR build (8 dispatches total in the whole pipeline) ----
    coarse_count<<<CBLK, 256, 0, stream>>>(dst, gcnt, x, xb);
    block_scan<<<CB, CBLK, 0, stream>>>(gcnt, btot);
    bucket_scan<<<1, 1024, 0, stream>>>(btot, bstart, add_pool);
    partition_k<<<CBLK, 256, 0, stream>>>(src, dst, gcnt, bstart, part);
    fine_sort<<<CB, 256, 0, stream>>>(part, bstart, ptr, esrc);

    // ---- Layer 1 ----
    gather_mlp1<<<2048, 256, 0, stream>>>(xb, x, ptr, esrc, w_rel1, b_rel1, w_root1, h1, h1f8);
    // ---- Layer 2 fused: gather + MFMA + pool ----
    gather2_mlp2_pool<<<2048, 256, 0, stream>>>((const unsigned*)h1f8, ptr, esrc, h1,
                                                w_rel2, b_rel2, w_root2, batch, add_pool);
    // ---- Head ----
    head_mlp<<<NUM_GRAPHS, 64, 0, stream>>>(add_pool, batch, w_h1, b_h1, w_h2, b_h2, out);
}

// Round 18
// 228.667 us; speedup vs baseline: 1.0762x; 1.0762x over previous
//
#include <hip/hip_runtime.h>
#include <hip/hip_bf16.h>

#define N_NODES    100000
#define N_EDGES    1200000
#define NUM_GRAPHS 128
#define IN_DIM     5
#define HIDDEN     64
#define M_TILES    (N_NODES / 16)   // 6250 (exact)
#define NI4        (N_EDGES / 4)    // 300000 int4 groups

#define CB    782                   // coarse buckets: ceil(N/128)
#define CBLK  256                   // partition blocks
#define EPB   ((NI4 + CBLK - 1) / CBLK)   // 1172 int4-groups per block

typedef __attribute__((ext_vector_type(8))) short short8;   // 8 bf16 (4 VGPRs)
typedef __attribute__((ext_vector_type(4))) float f32x4;

__device__ __forceinline__ int rfl(int v) { return __builtin_amdgcn_readfirstlane(v); }

// fp32 -> bf16 bits (RNE)
__device__ __forceinline__ unsigned short f2bs(float f) {
    union { float f; unsigned u; } v; v.f = f;
    return (unsigned short)((v.u + 0x7FFFu + ((v.u >> 16) & 1u)) >> 16);
}
// bf16 bits -> fp32
__device__ __forceinline__ float bs2f(unsigned short s) {
    union { unsigned u; float f; } v; v.u = ((unsigned)s) << 16;
    return v.f;
}
__device__ __forceinline__ float blo(unsigned p) { return bs2f((unsigned short)(p & 0xffff)); }
__device__ __forceinline__ float bhi(unsigned p) { return bs2f((unsigned short)(p >> 16)); }
__device__ __forceinline__ unsigned pack2(float a, float b) {
    return ((unsigned)f2bs(b) << 16) | (unsigned)f2bs(a);
}

// fp32 (>=0) -> fp8 e4m3 bits, RNE, denorm-exact (magic-multiply trick)
__device__ __forceinline__ unsigned char f2f8(float f) {
    union { float f; unsigned u; } v; v.f = f * 0x1p-120f;
    unsigned u = v.u + 0x7FFFFu + ((v.u >> 20) & 1u);
    return (unsigned char)(u >> 20);
}
// fp8 e4m3 bits -> fp32 (exact inverse)
__device__ __forceinline__ float f82f(unsigned b) {
    union { unsigned u; float f; } v; v.u = (b & 0x7Fu) << 20;
    return v.f * 0x1p120f;
}

// ==================== CSR build: two-level counting sort ====================
// part entries are PACKED 4B: src (bits 0..16) | (dst & 127) << 17.

// ---- Pass A: coarse histogram (dst>>7) + packx fold ------------------------
__global__ void coarse_count(const int* __restrict__ dst, int* __restrict__ gcnt,
                             const float* __restrict__ x, uint4* __restrict__ xb) {
    __shared__ int h[CB];
    int t = threadIdx.x, b = blockIdx.x;
    for (int i = t; i < CB; i += 256) h[i] = 0;
    __syncthreads();
    int i0 = b * EPB, i1 = min(i0 + EPB, NI4);
    for (int i = i0 + t; i < i1; i += 256) {
        int4 d = ((const int4*)dst)[i];
        atomicAdd(&h[d.x >> 7], 1);
        atomicAdd(&h[d.y >> 7], 1);
        atomicAdd(&h[d.z >> 7], 1);
        atomicAdd(&h[d.w >> 7], 1);
    }
    __syncthreads();
    for (int i = t; i < CB; i += 256) gcnt[b * CB + i] = h[i];

    // fold: pack x rows into 16B (5 bf16 + pad) for the layer-1 edge gather
    for (int n = b * 256 + t; n < N_NODES; n += CBLK * 256) {
        const float* xr = x + (size_t)n * IN_DIM;
        uint4 o;
        o.x = pack2(xr[0], xr[1]);
        o.y = pack2(xr[2], xr[3]);
        o.z = pack2(xr[4], 0.0f);
        o.w = 0u;
        xb[n] = o;
    }
}

// ---- Pass B1: per-bucket exclusive scan over the 256 blocks ---------------
__global__ void block_scan(int* __restrict__ gcnt, int* __restrict__ btot) {
    __shared__ int s[CBLK];
    int k = blockIdx.x, t = threadIdx.x;
    int v = gcnt[t * CB + k];
    s[t] = v;
    __syncthreads();
    for (int off = 1; off < CBLK; off <<= 1) {
        int x = (t >= off) ? s[t - off] : 0;
        __syncthreads();
        s[t] += x;
        __syncthreads();
    }
    gcnt[t * CB + k] = s[t] - v;
    if (t == CBLK - 1) btot[k] = s[t];
}

// ---- Pass B2: scan bucket totals -> bstart; also zero add_pool -------------
__global__ void bucket_scan(const int* __restrict__ btot, int* __restrict__ bstart,
                            float* __restrict__ add_pool) {
    __shared__ int s[1024];
    int t = threadIdx.x;
    int v = (t < CB) ? btot[t] : 0;
    s[t] = v;
    __syncthreads();
    for (int off = 1; off < 1024; off <<= 1) {
        int x = (t >= off) ? s[t - off] : 0;
        __syncthreads();
        s[t] += x;
        __syncthreads();
    }
    if (t < CB) bstart[t] = s[t] - v;
    if (t == 0) bstart[CB] = N_EDGES;
    for (int i = t; i < NUM_GRAPHS * HIDDEN; i += 1024) add_pool[i] = 0.0f;
}

// ---- Pass C: partition edges into coarse-bucket order (packed 4B) ----------
__global__ void partition_k(const int* __restrict__ src, const int* __restrict__ dst,
                            const int* __restrict__ gcnt, const int* __restrict__ bstart,
                            int* __restrict__ part) {
    __shared__ int base[CB];
    __shared__ int h[CB];
    int t = threadIdx.x, b = blockIdx.x;
    for (int i = t; i < CB; i += 256) {
        base[i] = bstart[i] + gcnt[b * CB + i];
        h[i] = 0;
    }
    __syncthreads();
    int i0 = b * EPB, i1 = min(i0 + EPB, NI4);
    for (int i = i0 + t; i < i1; i += 256) {
        int4 s4 = ((const int4*)src)[i];
        int4 d4 = ((const int4*)dst)[i];
        int k, r;
        k = d4.x >> 7; r = atomicAdd(&h[k], 1); part[base[k] + r] = s4.x | ((d4.x & 127) << 17);
        k = d4.y >> 7; r = atomicAdd(&h[k], 1); part[base[k] + r] = s4.y | ((d4.y & 127) << 17);
        k = d4.z >> 7; r = atomicAdd(&h[k], 1); part[base[k] + r] = s4.z | ((d4.z & 127) << 17);
        k = d4.w >> 7; r = atomicAdd(&h[k], 1); part[base[k] + r] = s4.w | ((d4.w & 127) << 17);
    }
}

// ---- Pass D: fine sort within each 128-node bucket -> ptr + esrc -----------
__global__ void fine_sort(const int* __restrict__ part, const int* __restrict__ bstart,
                          int* __restrict__ ptr, int* __restrict__ esrc) {
    __shared__ int fh[128];
    __shared__ int fr[128];
    int k = blockIdx.x, t = threadIdx.x;
    int e0 = bstart[k], e1 = bstart[k + 1];
    if (t < 128) { fh[t] = 0; fr[t] = 0; }
    __syncthreads();
    for (int e = e0 + t; e < e1; e += 256)
        atomicAdd(&fh[(part[e] >> 17) & 127], 1);
    __syncthreads();
    if (t == 0) {
        int run = 0;
        for (int i = 0; i < 128; ++i) { int c = fh[i]; fh[i] = run; run += c; }
    }
    __syncthreads();
    int n0 = k << 7;
    if (t < 128 && n0 + t < N_NODES) ptr[n0 + t] = e0 + fh[t];
    for (int e = e0 + t; e < e1; e += 256) {
        int p = part[e];
        int d = (p >> 17) & 127;
        int r = atomicAdd(&fr[d], 1);
        esrc[e0 + fh[d] + r] = p & 0x1FFFF;
    }
}

// ==================== GNN compute ===========================================

// ---- Layer 1: gather agg1 (ONE uint4 load per edge) + transform ------------
__global__ void gather_mlp1(const uint4* __restrict__ xb,
                            const float* __restrict__ x,
                            const int* __restrict__ ptr,
                            const int* __restrict__ esrc,
                            const float* __restrict__ w_rel1,
                            const float* __restrict__ b_rel1,
                            const float* __restrict__ w_root1,
                            unsigned short* __restrict__ h1,
                            unsigned char* __restrict__ h1f8) {
    int lane = threadIdx.x & 63;
    int w    = (blockIdx.x * blockDim.x + threadIdx.x) >> 6;
    int nw   = (gridDim.x * blockDim.x) >> 6;

    float wr[IN_DIM], wo[IN_DIM];
#pragma unroll
    for (int k = 0; k < IN_DIM; ++k) {
        wr[k] = w_rel1[k * HIDDEN + lane];
        wo[k] = w_root1[k * HIDDEN + lane];
    }
    float bias = b_rel1[lane];

    for (int n = w; n < N_NODES; n += nw) {
        int start = rfl(ptr[n]);
        int end   = rfl((n + 1 < N_NODES) ? ptr[n + 1] : N_EDGES);
        float a[IN_DIM] = {0.f, 0.f, 0.f, 0.f, 0.f};
        for (int e = start + lane; e < end; e += 64) {
            uint4 p = xb[esrc[e]];
            a[0] += blo(p.x); a[1] += bhi(p.x);
            a[2] += blo(p.y); a[3] += bhi(p.y);
            a[4] += blo(p.z);
        }
#pragma unroll
        for (int k = 0; k < IN_DIM; ++k)
#pragma unroll
            for (int off = 1; off < 64; off <<= 1)
                a[k] += __shfl_xor(a[k], off, 64);
        float acc = bias;
#pragma unroll
        for (int k = 0; k < IN_DIM; ++k)
            acc += a[k] * wr[k] + x[(size_t)n * IN_DIM + k] * wo[k];
        float hv = fmaxf(acc, 0.0f);
        h1[(size_t)n * HIDDEN + lane]   = f2bs(hv);
        h1f8[(size_t)n * HIDDEN + lane] = f2f8(hv);
    }
}

// ---- Layer 2 aggregate from fp8 rows (64B = ONE cache line per row) --------
__global__ void gather2_fp8(const unsigned* __restrict__ h1f8,   // row = 16 dwords
                            const int* __restrict__ ptr,
                            const int* __restrict__ esrc,
                            uint2* __restrict__ agg2) {          // row = 16 uint2 (bf16x4)
    int lane = threadIdx.x & 63;
    int ql   = lane & 15;        // dword index within row
    int q    = lane >> 4;        // edge slot 0..3
    int w    = (blockIdx.x * blockDim.x + threadIdx.x) >> 6;
    int nw   = (gridDim.x * blockDim.x) >> 6;

    for (int n = w; n < N_NODES; n += nw) {
        int start = rfl(ptr[n]);
        int end   = rfl((n + 1 < N_NODES) ? ptr[n + 1] : N_EDGES);
        float4 a0 = {0.f,0.f,0.f,0.f}, a1 = a0, a2 = a0, a3 = a0;
        int e = start + q;
        for (; e + 12 < end; e += 16) {
            int s0 = esrc[e], s1 = esrc[e + 4], s2 = esrc[e + 8], s3 = esrc[e + 12];
            unsigned p0 = h1f8[(size_t)s0 * 16 + ql];
            unsigned p1 = h1f8[(size_t)s1 * 16 + ql];
            unsigned p2 = h1f8[(size_t)s2 * 16 + ql];
            unsigned p3 = h1f8[(size_t)s3 * 16 + ql];
            a0.x += f82f(p0); a0.y += f82f(p0 >> 8); a0.z += f82f(p0 >> 16); a0.w += f82f(p0 >> 24);
            a1.x += f82f(p1); a1.y += f82f(p1 >> 8); a1.z += f82f(p1 >> 16); a1.w += f82f(p1 >> 24);
            a2.x += f82f(p2); a2.y += f82f(p2 >> 8); a2.z += f82f(p2 >> 16); a2.w += f82f(p2 >> 24);
            a3.x += f82f(p3); a3.y += f82f(p3 >> 8); a3.z += f82f(p3 >> 16); a3.w += f82f(p3 >> 24);
        }
        for (; e < end; e += 4) {
            unsigned p = h1f8[(size_t)esrc[e] * 16 + ql];
            a0.x += f82f(p); a0.y += f82f(p >> 8); a0.z += f82f(p >> 16); a0.w += f82f(p >> 24);
        }
        float4 a;
        a.x = (a0.x + a1.x) + (a2.x + a3.x);
        a.y = (a0.y + a1.y) + (a2.y + a3.y);
        a.z = (a0.z + a1.z) + (a2.z + a3.z);
        a.w = (a0.w + a1.w) + (a2.w + a3.w);
        a.x += __shfl_xor(a.x, 16, 64); a.x += __shfl_xor(a.x, 32, 64);
        a.y += __shfl_xor(a.y, 16, 64); a.y += __shfl_xor(a.y, 32, 64);
        a.z += __shfl_xor(a.z, 16, 64); a.z += __shfl_xor(a.z, 32, 64);
        a.w += __shfl_xor(a.w, 16, 64); a.w += __shfl_xor(a.w, 32, 64);
        if (q == 0) {
            uint2 o;
            o.x = pack2(a.x, a.y);
            o.y = pack2(a.z, a.w);
            agg2[(size_t)n * 16 + ql] = o;   // 128B coalesced per quarter-wave
        }
    }
}

// ---- Layer 2 transform via MFMA, FUSED with add-pool -----------------------
__global__ void mlp2_pool(const unsigned short* __restrict__ agg2,
                          const unsigned short* __restrict__ h1,
                          const float* __restrict__ w_rel2,
                          const float* __restrict__ b_rel2,
                          const float* __restrict__ w_root2,
                          const int* __restrict__ batch,
                          float* __restrict__ add_pool) {
    int lane = threadIdx.x & 63;
    int wv   = threadIdx.x >> 6;
    int row  = lane & 15;
    int quad = lane >> 4;
    int n    = wv * 16 + row;           // this lane's output column

    short8 bwr[2], bwo[2];
#pragma unroll
    for (int s = 0; s < 2; ++s)
#pragma unroll
        for (int j = 0; j < 8; ++j) {
            int k = 32 * s + quad * 8 + j;
            bwr[s][j] = (short)f2bs(w_rel2[k * HIDDEN + n]);
            bwo[s][j] = (short)f2bs(w_root2[k * HIDDEN + n]);
        }
    float bias = b_rel2[n];

    for (int t = blockIdx.x; t < M_TILES; t += gridDim.x) {
        int m0 = t * 16;
        size_t rbase = (size_t)(m0 + row) * HIDDEN;
        short8 aa0 = *(const short8*)(agg2 + rbase + quad * 8);
        short8 aa1 = *(const short8*)(agg2 + rbase + 32 + quad * 8);
        short8 ah0 = *(const short8*)(h1   + rbase + quad * 8);
        short8 ah1 = *(const short8*)(h1   + rbase + 32 + quad * 8);

        f32x4 acc = {bias, bias, bias, bias};
        acc = __builtin_amdgcn_mfma_f32_16x16x32_bf16(aa0, bwr[0], acc, 0, 0, 0);
        acc = __builtin_amdgcn_mfma_f32_16x16x32_bf16(aa1, bwr[1], acc, 0, 0, 0);
        acc = __builtin_amdgcn_mfma_f32_16x16x32_bf16(ah0, bwo[0], acc, 0, 0, 0);
        acc = __builtin_amdgcn_mfma_f32_16x16x32_bf16(ah1, bwo[1], acc, 0, 0, 0);

        float hv0 = fmaxf(acc[0], 0.0f), hv1 = fmaxf(acc[1], 0.0f);
        float hv2 = fmaxf(acc[2], 0.0f), hv3 = fmaxf(acc[3], 0.0f);

        int gLo = batch[m0], gHi = batch[m0 + 15];
        if (gLo == gHi) {
            float s = (hv0 + hv1) + (hv2 + hv3);
            s += __shfl_xor(s, 16, 64);
            s += __shfl_xor(s, 32, 64);
            if (quad == 0)
                atomicAdd(&add_pool[gLo * HIDDEN + n], s);
        } else {
            int m = m0 + quad * 4;
            atomicAdd(&add_pool[batch[m]     * HIDDEN + n], hv0);
            atomicAdd(&add_pool[batch[m + 1] * HIDDEN + n], hv1);
            atomicAdd(&add_pool[batch[m + 2] * HIDDEN + n], hv2);
            atomicAdd(&add_pool[batch[m + 3] * HIDDEN + n], hv3);
        }
    }
}

// ---- MLP head: one block (64 threads) per graph ----------------------------
__device__ __forceinline__ int lower_bound_i(const int* a, int n, int v) {
    int lo = 0, hi = n;
    while (lo < hi) { int mid = (lo + hi) >> 1; if (a[mid] < v) lo = mid + 1; else hi = mid; }
    return lo;
}

__global__ void head_mlp(const float* __restrict__ add_pool,
                         const int* __restrict__ batch,
                         const float* __restrict__ w_h1,
                         const float* __restrict__ b_h1,
                         const float* __restrict__ w_h2,
                         const float* __restrict__ b_h2,
                         float* __restrict__ out) {
    int g = blockIdx.x, t = threadIdx.x;

    __shared__ int s_cnt;
    if (t == 0) {
        int start = lower_bound_i(batch, N_NODES, g);
        int end   = lower_bound_i(batch, N_NODES, g + 1);
        s_cnt = end - start;
    }
    __syncthreads();
    float cnt = fmaxf((float)s_cnt, 1.0f);

    __shared__ float sg[2 * HIDDEN];
    float add = add_pool[(size_t)g * HIDDEN + t];
    sg[t]          = add / cnt;   // mean_pool
    sg[HIDDEN + t] = add;         // add_pool
    __syncthreads();

    float hid = b_h1[t];
#pragma unroll 16
    for (int i = 0; i < 2 * HIDDEN; ++i)
        hid += sg[i] * w_h1[i * HIDDEN + t];
    hid = fmaxf(hid, 0.0f);

    float res = hid * w_h2[t];
    for (int off = 32; off > 0; off >>= 1)
        res += __shfl_down(res, off, 64);
    if (t == 0) out[g] = res + b_h2[0];
}

extern "C" void kernel_launch(void* const* d_in, const int* in_sizes, int n_in,
                              void* d_out, int out_size, void* d_ws, size_t ws_size,
                              hipStream_t stream) {
    const float* x       = (const float*)d_in[0];
    const int*   ei      = (const int*)d_in[1];
    const int*   src     = ei;
    const int*   dst     = ei + N_EDGES;
    const int*   batch   = (const int*)d_in[2];
    const float* w_rel1  = (const float*)d_in[3];
    const float* b_rel1  = (const float*)d_in[4];
    const float* w_root1 = (const float*)d_in[5];
    const float* w_rel2  = (const float*)d_in[6];
    const float* b_rel2  = (const float*)d_in[7];
    const float* w_root2 = (const float*)d_in[8];
    const float* w_h1    = (const float*)d_in[9];
    const float* b_h1    = (const float*)d_in[10];
    const float* w_h2    = (const float*)d_in[11];
    const float* b_h2    = (const float*)d_in[12];
    float* out = (float*)d_out;

    int* base = (int*)d_ws;
    int*   gcnt     = base;                                   // CBLK*CB
    int*   btot     = gcnt + ((CBLK * CB + 3) & ~3);          // CB
    int*   bstart   = btot + ((CB + 3) & ~3);                 // CB+1
    float* add_pool = (float*)(bstart + ((CB + 1 + 3) & ~3)); // 128*64 f32
    int*   ptr      = (int*)(add_pool + NUM_GRAPHS * HIDDEN); // N
    int*   part     = ptr + ((N_NODES + 3) & ~3);             // E packed ints
    int*   esrc     = part + N_EDGES;                         // E
    unsigned short* h1   = (unsigned short*)(esrc + N_EDGES); // N*64 bf16
    unsigned short* agg2 = h1 + (size_t)N_NODES * HIDDEN;     // N*64 bf16
    unsigned char*  h1f8 = (unsigned char*)(agg2 + (size_t)N_NODES * HIDDEN); // N*64 fp8
    uint4*          xb   = (uint4*)(h1f8 + (size_t)N_NODES * HIDDEN);         // N*16B

    // ---- CSR build (9 dispatches total in the whole pipeline) ----
    coarse_count<<<CBLK, 256, 0, stream>>>(dst, gcnt, x, xb);
    block_scan<<<CB, CBLK, 0, stream>>>(gcnt, btot);
    bucket_scan<<<1, 1024, 0, stream>>>(btot, bstart, add_pool);
    partition_k<<<CBLK, 256, 0, stream>>>(src, dst, gcnt, bstart, part);
    fine_sort<<<CB, 256, 0, stream>>>(part, bstart, ptr, esrc);

    // ---- Layer 1 ----
    gather_mlp1<<<2048, 256, 0, stream>>>(xb, x, ptr, esrc, w_rel1, b_rel1, w_root1, h1, h1f8);
    // ---- Layer 2 (separate gather and MFMA+pool: fusion regressed, r17) ----
    gather2_fp8<<<2048, 256, 0, stream>>>((const unsigned*)h1f8, ptr, esrc, (uint2*)agg2);
    mlp2_pool<<<2048, 256, 0, stream>>>(agg2, h1, w_rel2, b_rel2, w_root2, batch, add_pool);
    // ---- Head ----
    head_mlp<<<NUM_GRAPHS, 64, 0, stream>>>(add_pool, batch, w_h1, b_h1, w_h2, b_h2, out);
}